// Round 1
// baseline (409.574 us; speedup 1.0000x reference)
//
#include <hip/hip_runtime.h>

// B=16, S=4096, V=1024, fp32.
// Restructured: never materialize K/V.
//   q[b,o]   = pool[b]·Wq[o,:] + bq[o]
//   qks[b,v] = (1/64) * sum_d q[b,d] Wk[d,v]
//   c[b]     = (1/64) * q[b]·bk
//   a[b,s]   = qks[b]·bert[b,s] + c[b]
//   u[b,v]   = sum_s a[b,s] bert[b,s,v];  A[b] = sum_s a[b,s]
//   out[b,d] = Wv[d,:]·u[b] + bv[d]*A[b]

#define BB 16
#define SS 4096
#define VV 1024
#define V4 256   // VV/4

__device__ __forceinline__ float dot4(const float4& a, const float4& b) {
    return a.x*b.x + a.y*b.y + a.z*b.z + a.w*b.w;
}

__device__ __forceinline__ void axpy4(float a, const float4& x, float4& y) {
    y.x = fmaf(a, x.x, y.x); y.y = fmaf(a, x.y, y.y);
    y.z = fmaf(a, x.z, y.z); y.w = fmaf(a, x.w, y.w);
}

__device__ __forceinline__ float wave_allreduce(float v) {
#pragma unroll
    for (int off = 32; off > 0; off >>= 1)
        v += __shfl_xor(v, off, 64);
    return v;
}

// One wave per output element (b,o): dot over V=1024, coalesced float4.
__global__ __launch_bounds__(256) void k_qproj(const float* __restrict__ pool,
                                               const float* __restrict__ Wq,
                                               const float* __restrict__ bq,
                                               float* __restrict__ q) {
    int w = threadIdx.x >> 6, lane = threadIdx.x & 63;
    int idx = blockIdx.x * 4 + w;            // [0, B*V)
    int b = idx >> 10, o = idx & (VV - 1);
    const float4* p4 = (const float4*)pool + b * V4;
    const float4* w4 = (const float4*)Wq + (size_t)o * V4;
    float acc = 0.f;
#pragma unroll
    for (int i = 0; i < 4; ++i)
        acc += dot4(w4[i * 64 + lane], p4[i * 64 + lane]);
    acc = wave_allreduce(acc);
    if (lane == 0) q[idx] = acc + bq[o];
}

// c[b] = (q[b]·bk)/64. One wave per b.
__global__ __launch_bounds__(64) void k_qbk(const float* __restrict__ q,
                                            const float* __restrict__ bk,
                                            float* __restrict__ c) {
    int b = blockIdx.x, lane = threadIdx.x;
    const float4* q4 = (const float4*)q + b * V4;
    const float4* k4 = (const float4*)bk;
    float acc = 0.f;
#pragma unroll
    for (int i = 0; i < 4; ++i)
        acc += dot4(q4[i * 64 + lane], k4[i * 64 + lane]);
    acc = wave_allreduce(acc);
    if (lane == 0) c[b] = acc * 0.015625f;
}

// qks[b,v] = (1/64) * sum_d q[b,d] Wk[d,v].  Wk read exactly once (coalesced
// along v); q broadcast from LDS; d-range split across blocks, atomic combine.
__global__ __launch_bounds__(256) void k_qk(const float* __restrict__ q,
                                            const float* __restrict__ Wk,
                                            float* __restrict__ qks) {
    __shared__ float qs[BB][64];
    int vc = blockIdx.x & 3, dc = blockIdx.x >> 2;
    int dlo = dc * 64;
    for (int i = threadIdx.x; i < BB * 64; i += 256) {
        int b = i >> 6, dd = i & 63;
        qs[b][dd] = q[b * VV + dlo + dd];
    }
    __syncthreads();
    int v = (vc << 8) + threadIdx.x;
    float acc[BB];
#pragma unroll
    for (int b = 0; b < BB; ++b) acc[b] = 0.f;
    for (int dd = 0; dd < 64; ++dd) {
        float wk = Wk[(size_t)(dlo + dd) * VV + v];
#pragma unroll
        for (int b = 0; b < BB; ++b) acc[b] = fmaf(qs[b][dd], wk, acc[b]);
    }
#pragma unroll
    for (int b = 0; b < BB; ++b)
        atomicAdd(&qks[b * VV + v], acc[b] * 0.015625f);
}

// Fused attention pass: single read of bert (256 MB). Each wave owns 32
// consecutive s rows of one batch: a = qks·row + c (wave butterfly reduce,
// no barriers), then u += a*row in registers. Block-level LDS combine, then
// atomic add to global u / A.
__global__ __launch_bounds__(256) void k_main(const float* __restrict__ bert,
                                              const float* __restrict__ qks,
                                              const float* __restrict__ c,
                                              float* __restrict__ u,
                                              float* __restrict__ A) {
    int w = threadIdx.x >> 6, lane = threadIdx.x & 63;
    int b = blockIdx.x >> 5, sc = blockIdx.x & 31;   // 32 blocks per batch
    int s0 = sc * 128 + w * 32;                      // 32 s per wave
    const float4* qk4 = (const float4*)qks + b * V4;
    float4 k0 = qk4[lane], k1 = qk4[64 + lane], k2 = qk4[128 + lane], k3 = qk4[192 + lane];
    float cb = c[b];
    float4 u0 = {0,0,0,0}, u1 = {0,0,0,0}, u2 = {0,0,0,0}, u3 = {0,0,0,0};
    float asum = 0.f;
    const float4* base = (const float4*)bert + ((size_t)b * SS + s0) * V4;
#pragma unroll 4
    for (int s = 0; s < 32; ++s) {
        const float4* row = base + (size_t)s * V4;
        float4 x0 = row[lane], x1 = row[64 + lane], x2 = row[128 + lane], x3 = row[192 + lane];
        float p = dot4(k0, x0) + dot4(k1, x1) + dot4(k2, x2) + dot4(k3, x3);
        p = wave_allreduce(p);               // all lanes hold full sum
        float a = p + cb;
        axpy4(a, x0, u0); axpy4(a, x1, u1); axpy4(a, x2, u2); axpy4(a, x3, u3);
        asum += a;
    }
    // combine 4 waves in LDS, then one atomic per element per block
    __shared__ float4 uls[4][256];
    __shared__ float as_[4];
    uls[w][lane]       = u0;
    uls[w][64 + lane]  = u1;
    uls[w][128 + lane] = u2;
    uls[w][192 + lane] = u3;
    if (lane == 0) as_[w] = asum;
    __syncthreads();
    int t = threadIdx.x;
    float4 a0 = uls[0][t], a1 = uls[1][t], a2 = uls[2][t], a3 = uls[3][t];
    float* up = u + (size_t)b * VV + 4 * t;
    atomicAdd(up + 0, a0.x + a1.x + a2.x + a3.x);
    atomicAdd(up + 1, a0.y + a1.y + a2.y + a3.y);
    atomicAdd(up + 2, a0.z + a1.z + a2.z + a3.z);
    atomicAdd(up + 3, a0.w + a1.w + a2.w + a3.w);
    if (t == 0) atomicAdd(&A[b], as_[0] + as_[1] + as_[2] + as_[3]);
}

// out[b,d] = Wv[d,:]·u[b] + bv[d]*A[b].  One wave per output element.
__global__ __launch_bounds__(256) void k_out(const float* __restrict__ Wv,
                                             const float* __restrict__ bv,
                                             const float* __restrict__ u,
                                             const float* __restrict__ A,
                                             float* __restrict__ out) {
    int w = threadIdx.x >> 6, lane = threadIdx.x & 63;
    int idx = blockIdx.x * 4 + w;            // [0, B*V)
    int b = idx >> 10, d = idx & (VV - 1);
    const float4* u4 = (const float4*)u + b * V4;
    const float4* w4 = (const float4*)Wv + (size_t)d * V4;
    float acc = 0.f;
#pragma unroll
    for (int i = 0; i < 4; ++i)
        acc += dot4(w4[i * 64 + lane], u4[i * 64 + lane]);
    acc = wave_allreduce(acc);
    if (lane == 0) out[idx] = acc + bv[d] * A[b];
}

extern "C" void kernel_launch(void* const* d_in, const int* in_sizes, int n_in,
                              void* d_out, int out_size, void* d_ws, size_t ws_size,
                              hipStream_t stream) {
    const float* pool = (const float*)d_in[0];
    const float* bert = (const float*)d_in[1];
    const float* Wq   = (const float*)d_in[2];
    const float* bq   = (const float*)d_in[3];
    const float* Wk   = (const float*)d_in[4];
    const float* bk   = (const float*)d_in[5];
    const float* Wv   = (const float*)d_in[6];
    const float* bv   = (const float*)d_in[7];
    float* out = (float*)d_out;

    float* ws  = (float*)d_ws;
    float* q   = ws;            // 16384 floats
    float* qks = ws + 16384;    // 16384 floats (zeroed)
    float* u   = ws + 32768;    // 16384 floats (zeroed)
    float* A   = ws + 49152;    // 16 floats   (zeroed)
    float* c   = ws + 49168;    // 16 floats

    hipMemsetAsync(qks, 0, (16384 + 16384 + 16) * sizeof(float), stream);
    k_qproj<<<4096, 256, 0, stream>>>(pool, Wq, bq, q);
    k_qbk  <<<16,   64,  0, stream>>>(q, bk, c);
    k_qk   <<<64,   256, 0, stream>>>(q, Wk, qks);
    k_main <<<512,  256, 0, stream>>>(bert, qks, c, u, A);
    k_out  <<<4096, 256, 0, stream>>>(Wv, bv, u, A, out);
}